// Round 12
// baseline (64.269 us; speedup 1.0000x reference)
//
#include <hip/hip_runtime.h>
#include <math.h>

// Batched dynamic bicycle model, 10 substeps h=0.01f.
// R11 post-mortem: streaming-store policy inert (FETCH still 90MB); plateau
// at ~56us with 16 waves/CU. Compute/memory barely overlap (56 = 37.6 mem +
// ~0.8*VALU). R12: MAX TLP — 128-row wave tiles (1 packed chain, 2 rows/
// thread), 4608B LDS/wave -> 18.4KB/block -> 8 blocks/CU = 32 waves/CU
// (100%), __launch_bounds__(256,8) to cap VGPR at 64. Persistent waves,
// 4 tiles each, prefetch pipeline unchanged.

typedef float v2f __attribute__((ext_vector_type(2)));
typedef float f4  __attribute__((ext_vector_type(4)));
typedef unsigned int u4 __attribute__((ext_vector_type(4)));

#if __has_builtin(__builtin_amdgcn_make_buffer_rsrc) && __has_builtin(__builtin_amdgcn_raw_buffer_store_b128)
#define USE_BUFFER_STORE 1
#else
#define USE_BUFFER_STORE 0
#endif

__device__ __forceinline__ float med3(float x, float lo, float hi) {
    return __builtin_amdgcn_fmed3f(x, lo, hi);
}
__device__ __forceinline__ v2f vfma2(v2f a, v2f b, v2f c) {
    return __builtin_elementwise_fma(a, b, c);
}
__device__ __forceinline__ v2f vmax2(v2f a, v2f b) {
    return __builtin_elementwise_max(a, b);
}
__device__ __forceinline__ v2f vmin2(v2f a, v2f b) {
    return __builtin_elementwise_min(a, b);
}

__global__ __launch_bounds__(256, 8) void bicycle_kernel(
    const float* __restrict__ state_in,   // (B,9)
    const float* __restrict__ action_in,  // (B,2)
    float* __restrict__ out,              // (B,9)
    unsigned int out_bytes)
{
    constexpr float MAX_STEER = (float)(30.0 * 3.141592653589793 / 180.0); // 0.5235988
    constexpr float V_EFF_MIN = (float)(20.0 / 3.6);                       // 5.5555553
    constexpr float FY_F_MAX  = (float)(0.9 * 1500.0 * 9.81 * (1.6 / 2.8)); // 7567.7143
    constexpr float FY_R_MAX  = (float)(0.9 * 1500.0 * 9.81 * (1.2 / 2.8)); // 5675.7857
    constexpr float CK[11] = {1.0f, 0.9f, 0.81f, 0.729f, 0.6561f, 0.59049f,
                              0.531441f, 0.4782969f, 0.43046721f,
                              0.387420489f, 0.3486784401f};

    __shared__ float smem[4 * 1152];          // 4608 B per wave (128 rows x 9)

    const int tid  = threadIdx.x;
    const int wid  = tid >> 6;
    const int lane = tid & 63;
    float* ws  = smem + wid * 1152;
    f4*    ws4 = (f4*)ws;

    const size_t W = (size_t)blockIdx.x * 4 + wid;   // global wave id (0..8191)

#if USE_BUFFER_STORE
    __amdgpu_buffer_rsrc_t srd = __builtin_amdgcn_make_buffer_rsrc(
        (void*)out, (short)0, (int)out_bytes, 0x00020000);
#endif

    f4     pk[5];    // parked state loads for the NEXT tile (pk[4]: lanes<32)
    float2 actp[2];  // parked action loads for the NEXT tile

    auto loadp = [&](int t) {
        const size_t R = (W * 4 + (size_t)t) * 128;
        const f4* g4 = (const f4*)(state_in + R * 9);    // 288 f4 per tile
#pragma unroll
        for (int i = 0; i < 4; ++i) pk[i] = g4[lane + 64 * i];
        if (lane < 32) pk[4] = g4[256 + lane];
        const float2* a2 = (const float2*)action_in + R;
#pragma unroll
        for (int j = 0; j < 2; ++j) actp[j] = a2[lane + 64 * j];
    };
    auto commit = [&]() {
#pragma unroll
        for (int i = 0; i < 4; ++i) ws4[lane + 64 * i] = pk[i];
        if (lane < 32) ws4[256 + lane] = pk[4];
    };

    loadp(0);
    commit();

#pragma unroll
    for (int t = 0; t < 4; ++t) {
        // ---- consume tile-t actions BEFORE actp is overwritten ----
        v2f a_ref = (v2f){med3(actp[0].x, -6.0f, 3.0f),
                          med3(actp[1].x, -6.0f, 3.0f)};
        v2f d_ref = (v2f){med3(actp[0].y, -MAX_STEER, MAX_STEER),
                          med3(actp[1].y, -MAX_STEER, MAX_STEER)};

        // ---- transpose-read rows lane, lane+64 (stride 9: 2-way alias, free) ----
        const int r0 = lane * 9;
        const int r1 = (lane + 64) * 9;
        v2f x    = (v2f){ws[r0 + 0], ws[r1 + 0]};
        v2f y    = (v2f){ws[r0 + 1], ws[r1 + 1]};
        v2f psi  = (v2f){ws[r0 + 2], ws[r1 + 2]};
        v2f v    = vmax2((v2f){ws[r0 + 3], ws[r1 + 3]}, (v2f)(0.0f));
        v2f a0   = (v2f){ws[r0 + 4], ws[r1 + 4]};
        v2f dl0  = (v2f){med3(ws[r0 + 5], -MAX_STEER, MAX_STEER),
                         med3(ws[r1 + 5], -MAX_STEER, MAX_STEER)};
        v2f beta = (v2f){ws[r0 + 6], ws[r1 + 6]};
        v2f r    = (v2f){ws[r0 + 7], ws[r1 + 7]};
        v2f da = a0  - a_ref;          // a_k     = a_ref + 0.9^k * da
        v2f dd = dl0 - d_ref;          // delta_k = d_ref + 0.9^k * dd (clamp never binds)
        v2f cs, sn;
        {
            float s0, c0, s1, c1;
            __sincosf(psi.x + beta.x, &s0, &c0);
            __sincosf(psi.y + beta.y, &s1, &c1);
            cs = (v2f){c0, c1};
            sn = (v2f){s0, s1};
        }

        if (t < 3) loadp(t + 1);   // prefetch next tile under this tile's compute

        // ---- integrate: 10 substeps, one packed chain ----
#pragma unroll
        for (int k = 0; k < 10; ++k) {
            v2f ak = vfma2((v2f)(CK[k]), da, a_ref);
            v2f dk = vfma2((v2f)(CK[k]), dd, d_ref);
            v2f v_eff = vmax2(v, (v2f)(V_EFF_MIN));
            v2f inv_v = {__builtin_amdgcn_rcpf(v_eff.x), __builtin_amdgcn_rcpf(v_eff.y)};
            v2f tt = r * inv_v;
            v2f alpha_f = vfma2((v2f)(1.2f), tt, beta) - dk;
            v2f alpha_r = vfma2((v2f)(-1.6f), tt, beta);
            v2f F_yf = vmin2(vmax2(alpha_f * -80000.0f, (v2f)(-FY_F_MAX)), (v2f)(FY_F_MAX));
            v2f F_yr = vmin2(vmax2(alpha_r * -80000.0f, (v2f)(-FY_R_MAX)), (v2f)(FY_R_MAX));
            v2f beta_dot = vfma2(F_yf + F_yr, inv_v * (1.0f / 1500.0f), -r);
            v2f r_dot = vfma2((v2f)(1.2f), F_yf, F_yr * -1.6f) * (1.0f / 2250.0f);

            v2f vh = v * 0.01f;
            x = vfma2(vh, cs, x);
            y = vfma2(vh, sn, y);

            v2f d  = (r + beta_dot) * 0.01f;
            v2f cd = vfma2(d * d, (v2f)(-0.5f), (v2f)(1.0f));
            v2f cs_n = vfma2(cs, cd, -(sn * d));
            v2f sn_n = vfma2(sn, cd, cs * d);

            v    = vmax2(vfma2(ak, (v2f)(0.01f), v), (v2f)(0.0f));
            psi  = vfma2(r, (v2f)(0.01f), psi);
            beta = vfma2(beta_dot, (v2f)(0.01f), beta);
            r    = vfma2(r_dot, (v2f)(0.01f), r);
            cs = cs_n;
            sn = sn_n;
        }

        // ---- writeback rows (a_10/delta_10 via closed form) ----
        {
            v2f a10 = vfma2((v2f)(CK[10]), da, a_ref);
            v2f d10 = vfma2((v2f)(CK[10]), dd, d_ref);
            ws[r0 + 0] = x.x;     ws[r1 + 0] = x.y;
            ws[r0 + 1] = y.x;     ws[r1 + 1] = y.y;
            ws[r0 + 2] = psi.x;   ws[r1 + 2] = psi.y;
            ws[r0 + 3] = v.x;     ws[r1 + 3] = v.y;
            ws[r0 + 4] = a10.x;   ws[r1 + 4] = a10.y;
            ws[r0 + 5] = d10.x;   ws[r1 + 5] = d10.y;
            ws[r0 + 6] = beta.x;  ws[r1 + 6] = beta.y;
            ws[r0 + 7] = r.x;     ws[r1 + 7] = r.y;
            ws[r0 + 8] = d_ref.x; ws[r1 + 8] = d_ref.y;
        }

        // ---- readout + streaming store (fused, low reg pressure), then commit ----
        const size_t R = (W * 4 + (size_t)t) * 128;
#if USE_BUFFER_STORE
        const int voff = (int)(R * 36) + lane * 16;
#pragma unroll
        for (int i = 0; i < 4; ++i) {
            f4 s = ws4[lane + 64 * i];
            __builtin_amdgcn_raw_buffer_store_b128(
                __builtin_bit_cast(u4, s), srd, voff + i * 1024, 0, 19);
        }
        if (lane < 32) {
            f4 s = ws4[256 + lane];
            __builtin_amdgcn_raw_buffer_store_b128(
                __builtin_bit_cast(u4, s), srd, (int)(R * 36) + 4096 + lane * 16, 0, 19);
        }
#else
        f4* o4 = (f4*)(out + R * 9);
#pragma unroll
        for (int i = 0; i < 4; ++i)
            __builtin_nontemporal_store(ws4[lane + 64 * i], &o4[lane + 64 * i]);
        if (lane < 32)
            __builtin_nontemporal_store(ws4[256 + lane], &o4[256 + lane]);
#endif
        // DS in-order per wave: readout ds_reads above retire before these writes
        if (t < 3) commit();
    }
}

extern "C" void kernel_launch(void* const* d_in, const int* in_sizes, int n_in,
                              void* d_out, int out_size, void* d_ws, size_t ws_size,
                              hipStream_t stream) {
    const float* state  = (const float*)d_in[0];
    const float* action = (const float*)d_in[1];
    float* out = (float*)d_out;
    const int rows = in_sizes[0] / 9;          // 4194304
    // 2048 blocks x 4 waves x 4 tiles x 128 rows = rows, exact; 8 blocks/CU.
    const int grid = rows / 2048;              // 2048
    bicycle_kernel<<<grid, 256, 0, stream>>>(state, action, out,
                                             (unsigned int)out_size * 4u);
}

// Round 13
// 61.628 us; speedup vs baseline: 1.0428x; 1.0428x over previous
//
#include <hip/hip_runtime.h>
#include <math.h>

// Batched dynamic bicycle model, 10 substeps h=0.01f.
// R12 post-mortem: max-TLP regressed (more HBM traffic, worse L3 hit).
// R13: R11 structure + PREFETCH DEPTH 2. HBM-miss latency ~900cy > one
// compute phase (~600cy) -> depth-1 prefetch still stalls at commit's
// vmcnt wait. Two named register parks (A/B): tile t+2's loads issue at
// start of phase t; their commit waits at end of phase t+1 (~2 phases of
// cover). All deps C-level visible -> compiler's counted waitcnts stay
// correct.

typedef float v2f __attribute__((ext_vector_type(2)));
typedef float f4  __attribute__((ext_vector_type(4)));
typedef unsigned int u4 __attribute__((ext_vector_type(4)));

#if __has_builtin(__builtin_amdgcn_make_buffer_rsrc) && __has_builtin(__builtin_amdgcn_raw_buffer_store_b128)
#define USE_BUFFER_STORE 1
#else
#define USE_BUFFER_STORE 0
#endif

__device__ __forceinline__ float med3(float x, float lo, float hi) {
    return __builtin_amdgcn_fmed3f(x, lo, hi);
}
__device__ __forceinline__ v2f vfma2(v2f a, v2f b, v2f c) {
    return __builtin_elementwise_fma(a, b, c);
}
__device__ __forceinline__ v2f vmax2(v2f a, v2f b) {
    return __builtin_elementwise_max(a, b);
}
__device__ __forceinline__ v2f vmin2(v2f a, v2f b) {
    return __builtin_elementwise_min(a, b);
}

__global__ __launch_bounds__(256, 4) void bicycle_kernel(
    const float* __restrict__ state_in,   // (B,9)
    const float* __restrict__ action_in,  // (B,2)
    float* __restrict__ out,              // (B,9)
    unsigned int out_bytes)
{
    constexpr float MAX_STEER = (float)(30.0 * 3.141592653589793 / 180.0); // 0.5235988
    constexpr float V_EFF_MIN = (float)(20.0 / 3.6);                       // 5.5555553
    constexpr float FY_F_MAX  = (float)(0.9 * 1500.0 * 9.81 * (1.6 / 2.8)); // 7567.7143
    constexpr float FY_R_MAX  = (float)(0.9 * 1500.0 * 9.81 * (1.2 / 2.8)); // 5675.7857
    constexpr float CK[11] = {1.0f, 0.9f, 0.81f, 0.729f, 0.6561f, 0.59049f,
                              0.531441f, 0.4782969f, 0.43046721f,
                              0.387420489f, 0.3486784401f};

    __shared__ float smem[4 * 2304];          // 9216 B per wave, wave-private

    const int tid  = threadIdx.x;
    const int wid  = tid >> 6;
    const int lane = tid & 63;
    float* ws  = smem + wid * 2304;
    f4*    ws4 = (f4*)ws;

    const size_t W = (size_t)blockIdx.x * 4 + wid;   // global wave id

#if USE_BUFFER_STORE
    __amdgpu_buffer_rsrc_t srd = __builtin_amdgcn_make_buffer_rsrc(
        (void*)out, (short)0, (int)out_bytes, 0x00020000);
#endif

    // two register parks: even tiles -> A, odd tiles -> B (all static-indexed)
    f4     pkA[9], pkB[9];
    float2 actA[4], actB[4];

#define LOADP(PK, ACT, T) do {                                                 \
        const size_t R_ = (W * 4 + (size_t)(T)) * 256;                         \
        const f4* g4_ = (const f4*)(state_in + R_ * 9);                        \
        _Pragma("unroll")                                                      \
        for (int i = 0; i < 9; ++i) PK[i] = g4_[lane + 64 * i];                \
        const float2* a2_ = (const float2*)action_in + R_;                     \
        _Pragma("unroll")                                                      \
        for (int j = 0; j < 4; ++j) ACT[j] = a2_[lane + 64 * j];               \
    } while (0)

#define COMMIT(PK) do {                                                        \
        _Pragma("unroll")                                                      \
        for (int i = 0; i < 9; ++i) ws4[lane + 64 * i] = PK[i];                \
    } while (0)

    // ---- prologue: tiles 0 and 1 in flight; commit tile 0 ----
    LOADP(pkA, actA, 0);
    LOADP(pkB, actB, 1);
    COMMIT(pkA);

#pragma unroll
    for (int t = 0; t < 4; ++t) {
        const bool evenT = ((t & 1) == 0);

        // ---- consume this tile's actions (before park reuse) ----
        v2f a_ref[2], d_ref[2];
#pragma unroll
        for (int p = 0; p < 2; ++p) {
            const float2 c0 = evenT ? actA[2 * p + 0] : actB[2 * p + 0];
            const float2 c1 = evenT ? actA[2 * p + 1] : actB[2 * p + 1];
            a_ref[p] = (v2f){med3(c0.x, -6.0f, 3.0f), med3(c1.x, -6.0f, 3.0f)};
            d_ref[p] = (v2f){med3(c0.y, -MAX_STEER, MAX_STEER),
                             med3(c1.y, -MAX_STEER, MAX_STEER)};
        }

        // ---- depth-2 prefetch: issue tile t+2 into the park just freed ----
        if (t == 0) LOADP(pkA, actA, 2);
        if (t == 1) LOADP(pkB, actB, 3);

        // ---- transpose-read tile t (stride 9: 2-way bank alias, free) ----
        v2f x[2], y[2], psi[2], v[2], beta[2], r[2], cs[2], sn[2], da[2], dd[2];
#pragma unroll
        for (int p = 0; p < 2; ++p) {
            const int r0 = (lane + 64 * (2 * p + 0)) * 9;
            const int r1 = (lane + 64 * (2 * p + 1)) * 9;
            x[p]     = (v2f){ws[r0 + 0], ws[r1 + 0]};
            y[p]     = (v2f){ws[r0 + 1], ws[r1 + 1]};
            psi[p]   = (v2f){ws[r0 + 2], ws[r1 + 2]};
            v[p]     = vmax2((v2f){ws[r0 + 3], ws[r1 + 3]}, (v2f)(0.0f));
            v2f a0   = (v2f){ws[r0 + 4], ws[r1 + 4]};
            v2f dl0  = (v2f){med3(ws[r0 + 5], -MAX_STEER, MAX_STEER),
                             med3(ws[r1 + 5], -MAX_STEER, MAX_STEER)};
            beta[p]  = (v2f){ws[r0 + 6], ws[r1 + 6]};
            r[p]     = (v2f){ws[r0 + 7], ws[r1 + 7]};
            da[p] = a0  - a_ref[p];
            dd[p] = dl0 - d_ref[p];
            float s0, c0, s1, c1;
            __sincosf(psi[p].x + beta[p].x, &s0, &c0);
            __sincosf(psi[p].y + beta[p].y, &s1, &c1);
            cs[p] = (v2f){c0, c1};
            sn[p] = (v2f){s0, s1};
        }

        // ---- integrate: 10 substeps, 2 independent packed chains ----
#pragma unroll
        for (int k = 0; k < 10; ++k) {
#pragma unroll
            for (int p = 0; p < 2; ++p) {
                v2f ak = vfma2((v2f)(CK[k]), da[p], a_ref[p]);
                v2f dk = vfma2((v2f)(CK[k]), dd[p], d_ref[p]);
                v2f v_eff = vmax2(v[p], (v2f)(V_EFF_MIN));
                v2f inv_v = {__builtin_amdgcn_rcpf(v_eff.x), __builtin_amdgcn_rcpf(v_eff.y)};
                v2f tt = r[p] * inv_v;
                v2f alpha_f = vfma2((v2f)(1.2f), tt, beta[p]) - dk;
                v2f alpha_r = vfma2((v2f)(-1.6f), tt, beta[p]);
                v2f F_yf = vmin2(vmax2(alpha_f * -80000.0f, (v2f)(-FY_F_MAX)), (v2f)(FY_F_MAX));
                v2f F_yr = vmin2(vmax2(alpha_r * -80000.0f, (v2f)(-FY_R_MAX)), (v2f)(FY_R_MAX));
                v2f beta_dot = vfma2(F_yf + F_yr, inv_v * (1.0f / 1500.0f), -r[p]);
                v2f r_dot = vfma2((v2f)(1.2f), F_yf, F_yr * -1.6f) * (1.0f / 2250.0f);

                v2f vh = v[p] * 0.01f;
                x[p] = vfma2(vh, cs[p], x[p]);
                y[p] = vfma2(vh, sn[p], y[p]);

                v2f d  = (r[p] + beta_dot) * 0.01f;
                v2f cd = vfma2(d * d, (v2f)(-0.5f), (v2f)(1.0f));
                v2f cs_n = vfma2(cs[p], cd, -(sn[p] * d));
                v2f sn_n = vfma2(sn[p], cd, cs[p] * d);

                v[p]   = vmax2(vfma2(ak, (v2f)(0.01f), v[p]), (v2f)(0.0f));
                psi[p] = vfma2(r[p], (v2f)(0.01f), psi[p]);
                beta[p] = vfma2(beta_dot, (v2f)(0.01f), beta[p]);
                r[p]   = vfma2(r_dot, (v2f)(0.01f), r[p]);
                cs[p] = cs_n;
                sn[p] = sn_n;
            }
        }

        // ---- writeback rows (a_10/delta_10 via closed form) ----
#pragma unroll
        for (int p = 0; p < 2; ++p) {
            v2f a10 = vfma2((v2f)(CK[10]), da[p], a_ref[p]);
            v2f d10 = vfma2((v2f)(CK[10]), dd[p], d_ref[p]);
            const int r0 = (lane + 64 * (2 * p + 0)) * 9;
            const int r1 = (lane + 64 * (2 * p + 1)) * 9;
            ws[r0 + 0] = x[p].x;     ws[r1 + 0] = x[p].y;
            ws[r0 + 1] = y[p].x;     ws[r1 + 1] = y[p].y;
            ws[r0 + 2] = psi[p].x;   ws[r1 + 2] = psi[p].y;
            ws[r0 + 3] = v[p].x;     ws[r1 + 3] = v[p].y;
            ws[r0 + 4] = a10.x;      ws[r1 + 4] = a10.y;
            ws[r0 + 5] = d10.x;      ws[r1 + 5] = d10.y;
            ws[r0 + 6] = beta[p].x;  ws[r1 + 6] = beta[p].y;
            ws[r0 + 7] = r[p].x;     ws[r1 + 7] = r[p].y;
            ws[r0 + 8] = d_ref[p].x; ws[r1 + 8] = d_ref[p].y;
        }

        // ---- readout f4 + streaming stores ----
        f4 st[9];
#pragma unroll
        for (int i = 0; i < 9; ++i) st[i] = ws4[lane + 64 * i];

        const size_t R = (W * 4 + (size_t)t) * 256;
#if USE_BUFFER_STORE
        const int voff = (int)(R * 36) + lane * 16;
#pragma unroll
        for (int i = 0; i < 9; ++i)
            __builtin_amdgcn_raw_buffer_store_b128(
                __builtin_bit_cast(u4, st[i]), srd, voff + i * 1024, 0, 19);
#else
        f4* o4 = (f4*)(out + R * 9);
#pragma unroll
        for (int i = 0; i < 9; ++i)
            __builtin_nontemporal_store(st[i], &o4[lane + 64 * i]);
#endif

        // ---- commit tile t+1 (loads issued >= 2 phases ago -> no stall) ----
        if (t == 0 || t == 2) COMMIT(pkB);
        if (t == 1)           COMMIT(pkA);
    }

#undef LOADP
#undef COMMIT
}

extern "C" void kernel_launch(void* const* d_in, const int* in_sizes, int n_in,
                              void* d_out, int out_size, void* d_ws, size_t ws_size,
                              hipStream_t stream) {
    const float* state  = (const float*)d_in[0];
    const float* action = (const float*)d_in[1];
    float* out = (float*)d_out;
    const int rows = in_sizes[0] / 9;          // 4194304
    const int grid = rows / 4096;              // 1024 blocks; 4 waves x 4 tiles x 256 rows
    bicycle_kernel<<<grid, 256, 0, stream>>>(state, action, out,
                                             (unsigned int)out_size * 4u);
}

// Round 14
// 55.653 us; speedup vs baseline: 1.1548x; 1.1074x over previous
//
#include <hip/hip_runtime.h>
#include <math.h>

// Batched dynamic bicycle model, 10 substeps h=0.01f.
// R13 post-mortem: depth-2 prefetch spilled (VGPR cap 64, +16MB scratch
// writes) -> regressed. REVERT to R11 (best: 55.9us = 95.5% of the 6.29TB/s
// mixed-stream ceiling on the mandatory 335.6MB CU-side traffic).
// Structure: persistent waves, 4x256-row tiles, wave-private 9216B LDS,
// depth-1 reg-park prefetch, closed-form a/delta, tracked buffer stores.

typedef float v2f __attribute__((ext_vector_type(2)));
typedef float f4  __attribute__((ext_vector_type(4)));
typedef unsigned int u4 __attribute__((ext_vector_type(4)));

#if __has_builtin(__builtin_amdgcn_make_buffer_rsrc) && __has_builtin(__builtin_amdgcn_raw_buffer_store_b128)
#define USE_BUFFER_STORE 1
#else
#define USE_BUFFER_STORE 0
#endif

__device__ __forceinline__ float med3(float x, float lo, float hi) {
    return __builtin_amdgcn_fmed3f(x, lo, hi);
}
__device__ __forceinline__ v2f vfma2(v2f a, v2f b, v2f c) {
    return __builtin_elementwise_fma(a, b, c);
}
__device__ __forceinline__ v2f vmax2(v2f a, v2f b) {
    return __builtin_elementwise_max(a, b);
}
__device__ __forceinline__ v2f vmin2(v2f a, v2f b) {
    return __builtin_elementwise_min(a, b);
}

__global__ __launch_bounds__(256, 4) void bicycle_kernel(
    const float* __restrict__ state_in,   // (B,9)
    const float* __restrict__ action_in,  // (B,2)
    float* __restrict__ out,              // (B,9)
    unsigned int out_bytes)
{
    constexpr float MAX_STEER = (float)(30.0 * 3.141592653589793 / 180.0); // 0.5235988
    constexpr float V_EFF_MIN = (float)(20.0 / 3.6);                       // 5.5555553
    constexpr float FY_F_MAX  = (float)(0.9 * 1500.0 * 9.81 * (1.6 / 2.8)); // 7567.7143
    constexpr float FY_R_MAX  = (float)(0.9 * 1500.0 * 9.81 * (1.2 / 2.8)); // 5675.7857
    constexpr float CK[11] = {1.0f, 0.9f, 0.81f, 0.729f, 0.6561f, 0.59049f,
                              0.531441f, 0.4782969f, 0.43046721f,
                              0.387420489f, 0.3486784401f};

    __shared__ float smem[4 * 2304];          // 9216 B per wave, wave-private

    const int tid  = threadIdx.x;
    const int wid  = tid >> 6;
    const int lane = tid & 63;
    float* ws  = smem + wid * 2304;
    f4*    ws4 = (f4*)ws;

    const size_t W = (size_t)blockIdx.x * 4 + wid;   // global wave id

#if USE_BUFFER_STORE
    __amdgpu_buffer_rsrc_t srd = __builtin_amdgcn_make_buffer_rsrc(
        (void*)out, (short)0, (int)out_bytes, 0x00020000);
#endif

    f4     pk[9];    // parked state loads for the NEXT tile
    float2 actp[4];  // parked action loads for the NEXT tile

    auto loadp = [&](int t) {
        const size_t R = (W * 4 + (size_t)t) * 256;
        const f4* g4 = (const f4*)(state_in + R * 9);
#pragma unroll
        for (int i = 0; i < 9; ++i) pk[i] = g4[lane + 64 * i];
        const float2* a2 = (const float2*)action_in + R;
#pragma unroll
        for (int j = 0; j < 4; ++j) actp[j] = a2[lane + 64 * j];
    };
    auto commit = [&]() {
#pragma unroll
        for (int i = 0; i < 9; ++i) ws4[lane + 64 * i] = pk[i];
    };

    loadp(0);
    commit();

#pragma unroll
    for (int t = 0; t < 4; ++t) {
        // ---- consume tile-t actions BEFORE actp is overwritten ----
        v2f a_ref[2], d_ref[2];
#pragma unroll
        for (int p = 0; p < 2; ++p) {
            a_ref[p] = (v2f){med3(actp[2 * p + 0].x, -6.0f, 3.0f),
                             med3(actp[2 * p + 1].x, -6.0f, 3.0f)};
            d_ref[p] = (v2f){med3(actp[2 * p + 0].y, -MAX_STEER, MAX_STEER),
                             med3(actp[2 * p + 1].y, -MAX_STEER, MAX_STEER)};
        }

        // ---- transpose-read tile t (stride 9: 2-way bank alias, free) ----
        v2f x[2], y[2], psi[2], v[2], beta[2], r[2], cs[2], sn[2], da[2], dd[2];
#pragma unroll
        for (int p = 0; p < 2; ++p) {
            const int r0 = (lane + 64 * (2 * p + 0)) * 9;
            const int r1 = (lane + 64 * (2 * p + 1)) * 9;
            x[p]     = (v2f){ws[r0 + 0], ws[r1 + 0]};
            y[p]     = (v2f){ws[r0 + 1], ws[r1 + 1]};
            psi[p]   = (v2f){ws[r0 + 2], ws[r1 + 2]};
            v[p]     = vmax2((v2f){ws[r0 + 3], ws[r1 + 3]}, (v2f)(0.0f));
            v2f a0   = (v2f){ws[r0 + 4], ws[r1 + 4]};
            v2f dl0  = (v2f){med3(ws[r0 + 5], -MAX_STEER, MAX_STEER),
                             med3(ws[r1 + 5], -MAX_STEER, MAX_STEER)};
            beta[p]  = (v2f){ws[r0 + 6], ws[r1 + 6]};
            r[p]     = (v2f){ws[r0 + 7], ws[r1 + 7]};
            da[p] = a0  - a_ref[p];        // a_k     = a_ref + 0.9^k * da
            dd[p] = dl0 - d_ref[p];        // delta_k = d_ref + 0.9^k * dd (clamp never binds)
            float s0, c0, s1, c1;
            __sincosf(psi[p].x + beta[p].x, &s0, &c0);
            __sincosf(psi[p].y + beta[p].y, &s1, &c1);
            cs[p] = (v2f){c0, c1};
            sn[p] = (v2f){s0, s1};
        }

        if (t < 3) loadp(t + 1);   // prefetch next tile under this tile's compute

        // ---- integrate: 10 substeps, 2 independent packed chains ----
#pragma unroll
        for (int k = 0; k < 10; ++k) {
#pragma unroll
            for (int p = 0; p < 2; ++p) {
                v2f ak = vfma2((v2f)(CK[k]), da[p], a_ref[p]);
                v2f dk = vfma2((v2f)(CK[k]), dd[p], d_ref[p]);
                v2f v_eff = vmax2(v[p], (v2f)(V_EFF_MIN));
                v2f inv_v = {__builtin_amdgcn_rcpf(v_eff.x), __builtin_amdgcn_rcpf(v_eff.y)};
                v2f tt = r[p] * inv_v;
                v2f alpha_f = vfma2((v2f)(1.2f), tt, beta[p]) - dk;
                v2f alpha_r = vfma2((v2f)(-1.6f), tt, beta[p]);
                v2f F_yf = vmin2(vmax2(alpha_f * -80000.0f, (v2f)(-FY_F_MAX)), (v2f)(FY_F_MAX));
                v2f F_yr = vmin2(vmax2(alpha_r * -80000.0f, (v2f)(-FY_R_MAX)), (v2f)(FY_R_MAX));
                v2f beta_dot = vfma2(F_yf + F_yr, inv_v * (1.0f / 1500.0f), -r[p]);
                v2f r_dot = vfma2((v2f)(1.2f), F_yf, F_yr * -1.6f) * (1.0f / 2250.0f);

                v2f vh = v[p] * 0.01f;
                x[p] = vfma2(vh, cs[p], x[p]);
                y[p] = vfma2(vh, sn[p], y[p]);

                v2f d  = (r[p] + beta_dot) * 0.01f;
                v2f cd = vfma2(d * d, (v2f)(-0.5f), (v2f)(1.0f));
                v2f cs_n = vfma2(cs[p], cd, -(sn[p] * d));
                v2f sn_n = vfma2(sn[p], cd, cs[p] * d);

                v[p]   = vmax2(vfma2(ak, (v2f)(0.01f), v[p]), (v2f)(0.0f));
                psi[p] = vfma2(r[p], (v2f)(0.01f), psi[p]);
                beta[p] = vfma2(beta_dot, (v2f)(0.01f), beta[p]);
                r[p]   = vfma2(r_dot, (v2f)(0.01f), r[p]);
                cs[p] = cs_n;
                sn[p] = sn_n;
            }
        }

        // ---- writeback rows (a_10/delta_10 via closed form) ----
#pragma unroll
        for (int p = 0; p < 2; ++p) {
            v2f a10 = vfma2((v2f)(CK[10]), da[p], a_ref[p]);
            v2f d10 = vfma2((v2f)(CK[10]), dd[p], d_ref[p]);
            const int r0 = (lane + 64 * (2 * p + 0)) * 9;
            const int r1 = (lane + 64 * (2 * p + 1)) * 9;
            ws[r0 + 0] = x[p].x;     ws[r1 + 0] = x[p].y;
            ws[r0 + 1] = y[p].x;     ws[r1 + 1] = y[p].y;
            ws[r0 + 2] = psi[p].x;   ws[r1 + 2] = psi[p].y;
            ws[r0 + 3] = v[p].x;     ws[r1 + 3] = v[p].y;
            ws[r0 + 4] = a10.x;      ws[r1 + 4] = a10.y;
            ws[r0 + 5] = d10.x;      ws[r1 + 5] = d10.y;
            ws[r0 + 6] = beta[p].x;  ws[r1 + 6] = beta[p].y;
            ws[r0 + 7] = r[p].x;     ws[r1 + 7] = r[p].y;
            ws[r0 + 8] = d_ref[p].x; ws[r1 + 8] = d_ref[p].y;
        }

        // ---- readout f4 ----
        f4 st[9];
#pragma unroll
        for (int i = 0; i < 9; ++i) st[i] = ws4[lane + 64 * i];

        // ---- commit parked tile t+1 (all vmem tracked -> waits correct) ----
        if (t < 3) commit();

        // ---- streaming stores: tracked buffer_store with SC0|NT|SC1 ----
        const size_t R = (W * 4 + (size_t)t) * 256;
#if USE_BUFFER_STORE
        const int voff = (int)(R * 36) + lane * 16;   // byte offset, <151MB fits
#pragma unroll
        for (int i = 0; i < 9; ++i)
            __builtin_amdgcn_raw_buffer_store_b128(
                __builtin_bit_cast(u4, st[i]), srd, voff + i * 1024, 0, 19);
#else
        f4* o4 = (f4*)(out + R * 9);
#pragma unroll
        for (int i = 0; i < 9; ++i)
            __builtin_nontemporal_store(st[i], &o4[lane + 64 * i]);
#endif
    }
}

extern "C" void kernel_launch(void* const* d_in, const int* in_sizes, int n_in,
                              void* d_out, int out_size, void* d_ws, size_t ws_size,
                              hipStream_t stream) {
    const float* state  = (const float*)d_in[0];
    const float* action = (const float*)d_in[1];
    float* out = (float*)d_out;
    const int rows = in_sizes[0] / 9;          // 4194304
    const int grid = rows / 4096;              // 1024 blocks; 4 waves x 4 tiles x 256 rows
    bicycle_kernel<<<grid, 256, 0, stream>>>(state, action, out,
                                             (unsigned int)out_size * 4u);
}